// Round 2
// baseline (499.793 us; speedup 1.0000x reference)
//
#include <hip/hip_runtime.h>
#include <hip/hip_bf16.h>

namespace {
constexpr int NPTS  = 65536;
constexpr int KNB   = 16;
constexpr int CMID  = 16;
constexpr int CIN   = 64;
constexpr int CADD  = 3;
constexpr int COUT  = 128;
constexpr int KREAL = 1072;      // 67*16
constexpr int KPAD  = 1088;      // 68*16
constexpr int MT    = 16;        // points per block (back to 16: occupancy > Wb-reuse)
constexpr int ROWB  = KPAD * 2;  // s_p row stride in BYTES (2176, 16B-aligned, swizzled)
constexpr int NKT   = KPAD / 32; // 34
constexpr int NWAVE = 8;
constexpr int TSZ   = 256;       // one 16x16 bf16 tile = 256 shorts = 512 B
constexpr int PF    = 4;         // stage-2 Wb prefetch depth (static ring)
}

typedef __attribute__((ext_vector_type(8))) __bf16 bf16x8;
typedef __attribute__((ext_vector_type(4))) float f32x4;
typedef __attribute__((ext_vector_type(4))) float f32x4v;  // for nontemporal vec loads

union ABFrag { bf16x8 v; uint4 u; };

__device__ __forceinline__ unsigned short bf(float x) {
  __hip_bfloat16 h = __float2bfloat16(x);
  return *reinterpret_cast<unsigned short*>(&h);
}
__device__ __forceinline__ unsigned int pack_bf2(float a, float b) {
  __hip_bfloat162 h = __float22bfloat162_rn(make_float2(a, b));
  return *reinterpret_cast<unsigned int*>(&h);
}

// One-time per launch: W [128][1072] f32 -> bf16 zero-padded [128][1088].
__global__ void convert_w(const float* __restrict__ W, unsigned short* __restrict__ Wb) {
  const int o = blockIdx.x;
  for (int k = threadIdx.x; k < KPAD; k += blockDim.x) {
    float v = (k < KREAL) ? W[o * KREAL + k] : 0.0f;
    Wb[o * KPAD + k] = bf(v);
  }
}

// LDS: s_p 16*1088*2 = 34816 B, s_x (8*2*256+16)*2 = 8224 B -> 43040 B total.
// 3 blocks/CU (129120 <= 163840) x 8 waves = 24 waves/CU = 75% occupancy (was 45.8%).
// s_p uses XOR swizzle byte^=((row&7)<<4): stage-2 ds_read_b128 becomes 2-way (free, m136).
__global__ __launch_bounds__(512, 6) void pconv_fused(
    const float* __restrict__ feat,        // [2][65536][64]  (cacheable: LLC-resident)
    const int* __restrict__ nidx,          // [2][65536][16]  (nt: streamed once)
    const float* __restrict__ wn,          // [2][65536][16][16] (nt: streamed once)
    const float* __restrict__ addf,        // [2][65536][16][3]  (nt: streamed once)
    const float* __restrict__ W,           // [128][1072] f32 (fallback)
    const float* __restrict__ bias,        // [128]
    const unsigned short* __restrict__ Wb, // [128][1088] bf16 (cacheable: L2-reused)
    int useWb,
    float* __restrict__ out)               // [2][65536][128] (nt stores)
{
  __shared__ __align__(16) unsigned short s_p[MT * KPAD];             // 34816 B
  __shared__ __align__(16) unsigned short s_x[NWAVE * 2 * TSZ + 16];  // 8224 B

  char* s_pb = reinterpret_cast<char*>(s_p);

  const int tid  = threadIdx.x;
  const int wid  = tid >> 6;
  const int lane = tid & 63;
  const int q    = lane >> 4;
  const int l    = lane & 15;
  const int kq   = lane >> 2;   // stage-1: neighbor slot (0..15)
  const int sub  = lane & 3;    // stage-1: sub-slot

  // two ping-pong 16x16 tiles per wave; a tile is always consumed into
  // registers before the next write targets it (same-wave LDS is in-order).
  unsigned short* T0 = s_x + wid * (2 * TSZ);
  unsigned short* T1 = T0 + TSZ;

  // ---------------- stage 1: per-point MFMA pconv^T -> s_p ----------------
  {
    const int mg0 = blockIdx.x * MT + wid * 2;   // 8 waves x 2 points = 16
    const int b   = (blockIdx.x * MT) >> 16;     // whole block in one batch
    const float* fb = feat + (size_t)b * (NPTS * CIN);

    int nb[2];
#pragma unroll
    for (int pl = 0; pl < 2; ++pl)
      nb[pl] = __builtin_nontemporal_load(nidx + (size_t)(mg0 + pl) * KNB + kq);

    f32x4v wv[2];
    float  av[2];
#pragma unroll
    for (int pl = 0; pl < 2; ++pl) {
      const int mg = mg0 + pl;
      wv[pl] = __builtin_nontemporal_load(reinterpret_cast<const f32x4v*>(
          wn + (size_t)mg * (KNB * CMID) + kq * CMID + sub * 4));
      av[pl] = 0.f;
      if (sub < CADD)
        av[pl] = __builtin_nontemporal_load(
            addf + (size_t)mg * (KNB * CADD) + kq * CADD + sub);
    }

    // software-pipelined gather: point pl+1's feat rows in flight while pl processes
    f32x4v fvn[4];
    {
      const float* fr = fb + (size_t)nb[0] * CIN + sub * 4;
#pragma unroll
      for (int t = 0; t < 4; ++t)
        fvn[t] = *reinterpret_cast<const f32x4v*>(fr + 16 * t);
    }

    const f32x4 zacc = {0.f, 0.f, 0.f, 0.f};

#pragma unroll
    for (int pl = 0; pl < 2; ++pl) {
      f32x4v fv[4];
#pragma unroll
      for (int t = 0; t < 4; ++t) fv[t] = fvn[t];
      if (pl < 1) {
        const float* fr = fb + (size_t)nb[pl + 1] * CIN + sub * 4;
#pragma unroll
        for (int t = 0; t < 4; ++t)
          fvn[t] = *reinterpret_cast<const f32x4v*>(fr + 16 * t);
      }

      const int p = wid * 2 + pl;               // s_p row for this point
      char* prow = s_pb + p * ROWB;
      const int rsw = (p & 7) << 4;             // row XOR swizzle

      // wn^T -> T0 : row j = sub*4+i, col kq (k=0..15; k=16..31 are reg-zeros)
      T0[(sub * 4 + 0) * 16 + kq] = bf(wv[pl].x);
      T0[(sub * 4 + 1) * 16 + kq] = bf(wv[pl].y);
      T0[(sub * 4 + 2) * 16 + kq] = bf(wv[pl].z);
      T0[(sub * 4 + 3) * 16 + kq] = bf(wv[pl].w);
      // feat^T tile ct=0 -> T1 : row c = sub*4+e, col kq
      {
        unsigned short* d = T1 + (sub * 4) * 16 + kq;
        d[0 * 16] = bf(fv[0].x); d[1 * 16] = bf(fv[0].y);
        d[2 * 16] = bf(fv[0].z); d[3 * 16] = bf(fv[0].w);
      }

      // fragments: k-groups q<2 read real data, q>=2 are the K=32 zero padding (in regs)
      ABFrag fa, fb0;
      fa.u  = make_uint4(0, 0, 0, 0);
      fb0.u = make_uint4(0, 0, 0, 0);
      if (q < 2) {
        fa.v  = *reinterpret_cast<const bf16x8*>(T0 + l * 16 + q * 8);
        fb0.v = *reinterpret_cast<const bf16x8*>(T1 + l * 16 + q * 8);
      }

      // f1 -> T0 (wn already consumed into fa)
      {
        unsigned short* d = T0 + (sub * 4) * 16 + kq;
        d[0 * 16] = bf(fv[1].x); d[1 * 16] = bf(fv[1].y);
        d[2 * 16] = bf(fv[1].z); d[3 * 16] = bf(fv[1].w);
      }
      f32x4 d0 = __builtin_amdgcn_mfma_f32_16x16x32_bf16(fa.v, fb0.v, zacc, 0, 0, 0);
      { uint2 w2; w2.x = pack_bf2(d0[0], d0[1]); w2.y = pack_bf2(d0[2], d0[3]);
        *reinterpret_cast<uint2*>(prow + (((0 * 16 + l) * 32 + q * 8) ^ rsw)) = w2; }

      ABFrag fb1; fb1.u = make_uint4(0, 0, 0, 0);
      if (q < 2) fb1.v = *reinterpret_cast<const bf16x8*>(T0 + l * 16 + q * 8);
      // f2 -> T1 (f0 consumed)
      {
        unsigned short* d = T1 + (sub * 4) * 16 + kq;
        d[0 * 16] = bf(fv[2].x); d[1 * 16] = bf(fv[2].y);
        d[2 * 16] = bf(fv[2].z); d[3 * 16] = bf(fv[2].w);
      }
      f32x4 d1 = __builtin_amdgcn_mfma_f32_16x16x32_bf16(fa.v, fb1.v, zacc, 0, 0, 0);
      { uint2 w2; w2.x = pack_bf2(d1[0], d1[1]); w2.y = pack_bf2(d1[2], d1[3]);
        *reinterpret_cast<uint2*>(prow + (((1 * 16 + l) * 32 + q * 8) ^ rsw)) = w2; }

      ABFrag fb2; fb2.u = make_uint4(0, 0, 0, 0);
      if (q < 2) fb2.v = *reinterpret_cast<const bf16x8*>(T1 + l * 16 + q * 8);
      // f3 -> T0 (f1 consumed)
      {
        unsigned short* d = T0 + (sub * 4) * 16 + kq;
        d[0 * 16] = bf(fv[3].x); d[1 * 16] = bf(fv[3].y);
        d[2 * 16] = bf(fv[3].z); d[3 * 16] = bf(fv[3].w);
      }
      f32x4 d2 = __builtin_amdgcn_mfma_f32_16x16x32_bf16(fa.v, fb2.v, zacc, 0, 0, 0);
      { uint2 w2; w2.x = pack_bf2(d2[0], d2[1]); w2.y = pack_bf2(d2[2], d2[3]);
        *reinterpret_cast<uint2*>(prow + (((2 * 16 + l) * 32 + q * 8) ^ rsw)) = w2; }

      ABFrag fb3; fb3.u = make_uint4(0, 0, 0, 0);
      if (q < 2) fb3.v = *reinterpret_cast<const bf16x8*>(T0 + l * 16 + q * 8);
      // addf tile -> T1 (f2 consumed): rows 0..2 = av, rows 3..15 = 0
      {
        if (lane < 52)
          *reinterpret_cast<uint2*>(T1 + (3 + (lane >> 2)) * 16 + (lane & 3) * 4) =
              make_uint2(0u, 0u);
        if (sub < CADD)
          T1[sub * 16 + kq] = bf(av[pl]);
      }
      f32x4 d3 = __builtin_amdgcn_mfma_f32_16x16x32_bf16(fa.v, fb3.v, zacc, 0, 0, 0);
      { uint2 w2; w2.x = pack_bf2(d3[0], d3[1]); w2.y = pack_bf2(d3[2], d3[3]);
        *reinterpret_cast<uint2*>(prow + (((3 * 16 + l) * 32 + q * 8) ^ rsw)) = w2; }

      ABFrag fb4; fb4.u = make_uint4(0, 0, 0, 0);
      if (q < 2) fb4.v = *reinterpret_cast<const bf16x8*>(T1 + l * 16 + q * 8);
      f32x4 d4 = __builtin_amdgcn_mfma_f32_16x16x32_bf16(fa.v, fb4.v, zacc, 0, 0, 0);
      if (l < 4) {  // c = 64..67 (67 is the K-pad row, genuinely zero)
        uint2 w2; w2.x = pack_bf2(d4[0], d4[1]); w2.y = pack_bf2(d4[2], d4[3]);
        *reinterpret_cast<uint2*>(prow + (((4 * 16 + l) * 32 + q * 8) ^ rsw)) = w2;
      }
    }
  }

  __syncthreads();  // the ONLY barrier

  // ---------------- stage 2: out[16][128] = pconv[16][1088] @ Wb^T ----------------
  // each wave: 16 output channels x 16 points; Wb streamed from L2 with a
  // static 4-deep prefetch ring (fully unrolled -> compile-time indices).
  const int ob = wid * 16;
  const float bv = bias[ob + l];

  f32x4 acc = {0.f, 0.f, 0.f, 0.f};

  const unsigned short* wp = Wb + (size_t)(ob + l) * KPAD + q * 8;
  const float* wf = W + (size_t)(ob + l) * KREAL + q * 8;
  const int asw = (l & 7) << 4;  // A-row swizzle (row = point = l)

  if (useWb) {
    ABFrag wb[PF];
#pragma unroll
    for (int i = 0; i < PF; ++i)
      wb[i].u = *reinterpret_cast<const uint4*>(wp + i * 32);
#pragma unroll
    for (int kt = 0; kt < NKT; ++kt) {
      ABFrag cur = wb[kt & (PF - 1)];
      if (kt + PF < NKT)
        wb[kt & (PF - 1)].u = *reinterpret_cast<const uint4*>(wp + (kt + PF) * 32);
      const bf16x8 a = *reinterpret_cast<const bf16x8*>(
          s_pb + l * ROWB + ((kt * 64 + q * 16) ^ asw));
      acc = __builtin_amdgcn_mfma_f32_16x16x32_bf16(a, cur.v, acc, 0, 0, 0);
    }
  } else {
#pragma unroll 2
    for (int kt = 0; kt < NKT; ++kt) {
      const bf16x8 a = *reinterpret_cast<const bf16x8*>(
          s_pb + l * ROWB + ((kt * 64 + q * 16) ^ asw));
      const int kb = kt * 32 + q * 8;
      ABFrag bb;
      bb.u = make_uint4(0, 0, 0, 0);
      if (kb < KREAL) {
        const float4* s0 = reinterpret_cast<const float4*>(wf + kt * 32);
        const float4 x0 = s0[0], x1 = s0[1];
        bb.u = make_uint4(pack_bf2(x0.x, x0.y), pack_bf2(x0.z, x0.w),
                          pack_bf2(x1.x, x1.y), pack_bf2(x1.z, x1.w));
      }
      acc = __builtin_amdgcn_mfma_f32_16x16x32_bf16(a, bb.v, acc, 0, 0, 0);
    }
  }

  // epilogue: nt stores (out is never re-read)
  const int m0 = blockIdx.x * MT;
#pragma unroll
  for (int r = 0; r < 4; ++r)
    __builtin_nontemporal_store(acc[r] + bv,
        out + (size_t)(m0 + q * 4 + r) * COUT + ob + l);
}

extern "C" void kernel_launch(void* const* d_in, const int* in_sizes, int n_in,
                              void* d_out, int out_size, void* d_ws, size_t ws_size,
                              hipStream_t stream) {
  const float* feat = (const float*)d_in[0];
  const int*   nidx = (const int*)d_in[1];
  const float* wn   = (const float*)d_in[2];
  const float* addf = (const float*)d_in[3];
  const float* W    = (const float*)d_in[4];
  const float* bias = (const float*)d_in[5];
  float* out = (float*)d_out;

  unsigned short* Wb = (unsigned short*)d_ws;
  const int useWb = (ws_size >= (size_t)COUT * KPAD * 2) ? 1 : 0;
  if (useWb) {
    convert_w<<<COUT, 256, 0, stream>>>(W, Wb);
  }
  const int nblocks = (2 * NPTS) / MT;  // 8192
  pconv_fused<<<nblocks, 512, 0, stream>>>(feat, nidx, wn, addf, W, bias, Wb, useWb, out);
}

// Round 3
// 380.516 us; speedup vs baseline: 1.3135x; 1.3135x over previous
//
#include <hip/hip_runtime.h>
#include <hip/hip_bf16.h>

namespace {
constexpr int NPTS  = 65536;
constexpr int KNB   = 16;
constexpr int CMID  = 16;
constexpr int CIN   = 64;
constexpr int CADD  = 3;
constexpr int COUT  = 128;
constexpr int KREAL = 1072;      // 67*16
constexpr int KPAD  = 1088;      // 68*16
constexpr int MT    = 32;        // points per block (R1-proven)
constexpr int PSTR  = 1092;      // s_p row stride (shorts)
constexpr int NKT   = KPAD / 32; // 34
constexpr int NWAVE = 8;
constexpr int TSTR  = 20;        // scratch tile row stride in shorts (40 B = 10 banks: breaks
                                 // the 32B-row wrap that made transpose stores 8-way conflicted)
constexpr int TSZ   = 16 * TSTR; // 320 shorts per tile
constexpr int PF    = 4;         // stage-2 Wb prefetch ring depth
}

typedef __attribute__((ext_vector_type(8))) __bf16 bf16x8;
typedef __attribute__((ext_vector_type(4))) float f32x4;
typedef __attribute__((ext_vector_type(4))) float f32x4v;  // for nontemporal vec loads

union ABFrag { bf16x8 v; uint4 u; };

__device__ __forceinline__ unsigned short bf(float x) {
  __hip_bfloat16 h = __float2bfloat16(x);
  return *reinterpret_cast<unsigned short*>(&h);
}
__device__ __forceinline__ unsigned int pack_bf2(float a, float b) {
  __hip_bfloat162 h = __float22bfloat162_rn(make_float2(a, b));
  return *reinterpret_cast<unsigned int*>(&h);
}

// One-time per launch: W [128][1072] f32 -> bf16 zero-padded [128][1088].
__global__ void convert_w(const float* __restrict__ W, unsigned short* __restrict__ Wb) {
  const int o = blockIdx.x;
  for (int k = threadIdx.x; k < KPAD; k += blockDim.x) {
    float v = (k < KREAL) ? W[o * KREAL + k] : 0.0f;
    Wb[o * KPAD + k] = bf(v);
  }
}

// LDS: s_p 32*1092*2 = 69888 B, s_x (8*2*320+16)*2 = 10272 B -> 80160 B total.
// 2 blocks/CU (160320 <= 163840) x 8 waves = 16 waves/CU (R1's proven occupancy).
__global__ __launch_bounds__(512, 4) void pconv_fused(
    const float* __restrict__ feat,        // [2][65536][64]  (cacheable: LLC-resident)
    const int* __restrict__ nidx,          // [2][65536][16]  (nt: streamed once)
    const float* __restrict__ wn,          // [2][65536][16][16] (nt: streamed once)
    const float* __restrict__ addf,        // [2][65536][16][3]  (nt: streamed once)
    const float* __restrict__ W,           // [128][1072] f32 (fallback)
    const float* __restrict__ bias,        // [128]
    const unsigned short* __restrict__ Wb, // [128][1088] bf16 (cacheable: L2-reused)
    int useWb,
    float* __restrict__ out)               // [2][65536][128] (nt stores)
{
  __shared__ __align__(16) unsigned short s_p[MT * PSTR];             // 69888 B
  __shared__ __align__(16) unsigned short s_x[NWAVE * 2 * TSZ + 16];  // 10272 B

  const int tid  = threadIdx.x;
  const int wid  = tid >> 6;
  const int lane = tid & 63;
  const int q    = lane >> 4;
  const int l    = lane & 15;
  const int kq   = lane >> 2;   // stage-1: neighbor slot (0..15)
  const int sub  = lane & 3;    // stage-1: sub-slot

  // two ping-pong 16x16 tiles per wave (row stride TSTR=20 shorts -> transpose
  // stores land on 32 distinct banks, 2 lanes each = conflict-free).
  unsigned short* T0 = s_x + wid * (2 * TSZ);
  unsigned short* T1 = T0 + TSZ;

  // ---------------- stage 1: per-point MFMA pconv^T -> s_p ----------------
  {
    const int mg0 = blockIdx.x * MT + wid * 4;
    const int b   = (blockIdx.x * MT) >> 16;   // whole block in one batch
    const float* fb = feat + (size_t)b * (NPTS * CIN);

    int nb[4];
#pragma unroll
    for (int pl = 0; pl < 4; ++pl)
      nb[pl] = __builtin_nontemporal_load(nidx + (size_t)(mg0 + pl) * KNB + kq);

    f32x4v wv[4];
    float  av[4];
#pragma unroll
    for (int pl = 0; pl < 4; ++pl) {
      const int mg = mg0 + pl;
      wv[pl] = __builtin_nontemporal_load(reinterpret_cast<const f32x4v*>(
          wn + (size_t)mg * (KNB * CMID) + kq * CMID + sub * 4));
      av[pl] = 0.f;
      if (sub < CADD)
        av[pl] = __builtin_nontemporal_load(
            addf + (size_t)mg * (KNB * CADD) + kq * CADD + sub);
    }

    // software-pipelined gather: feat rows for point pl+1 in flight while pl processes
    f32x4v fvn[4];
    {
      const float* fr = fb + (size_t)nb[0] * CIN + sub * 4;
#pragma unroll
      for (int t = 0; t < 4; ++t)
        fvn[t] = *reinterpret_cast<const f32x4v*>(fr + 16 * t);
    }

    const f32x4 zacc = {0.f, 0.f, 0.f, 0.f};

#pragma unroll
    for (int pl = 0; pl < 4; ++pl) {
      f32x4v fv[4];
#pragma unroll
      for (int t = 0; t < 4; ++t) fv[t] = fvn[t];
      if (pl < 3) {
        const float* fr = fb + (size_t)nb[pl + 1] * CIN + sub * 4;
#pragma unroll
        for (int t = 0; t < 4; ++t)
          fvn[t] = *reinterpret_cast<const f32x4v*>(fr + 16 * t);
      }

      unsigned short* prow = s_p + (wid * 4 + pl) * PSTR;

      // wn^T -> T0 : row j = sub*4+i, col kq (cols k=0..15; k=16..31 are reg-zeros)
      T0[(sub * 4 + 0) * TSTR + kq] = bf(wv[pl].x);
      T0[(sub * 4 + 1) * TSTR + kq] = bf(wv[pl].y);
      T0[(sub * 4 + 2) * TSTR + kq] = bf(wv[pl].z);
      T0[(sub * 4 + 3) * TSTR + kq] = bf(wv[pl].w);
      // feat^T tile ct=0 -> T1 : row c = sub*4+e, col kq
      {
        unsigned short* d = T1 + (sub * 4) * TSTR + kq;
        d[0 * TSTR] = bf(fv[0].x); d[1 * TSTR] = bf(fv[0].y);
        d[2 * TSTR] = bf(fv[0].z); d[3 * TSTR] = bf(fv[0].w);
      }

      // fragments: k-groups q<2 read real data, q>=2 are the K=32 zero padding (in regs)
      ABFrag fa, fb0;
      fa.u  = make_uint4(0, 0, 0, 0);
      fb0.u = make_uint4(0, 0, 0, 0);
      if (q < 2) {
        fa.v  = *reinterpret_cast<const bf16x8*>(T0 + l * TSTR + q * 8);
        fb0.v = *reinterpret_cast<const bf16x8*>(T1 + l * TSTR + q * 8);
      }

      // f1 -> T0 (wn already consumed into fa)
      {
        unsigned short* d = T0 + (sub * 4) * TSTR + kq;
        d[0 * TSTR] = bf(fv[1].x); d[1 * TSTR] = bf(fv[1].y);
        d[2 * TSTR] = bf(fv[1].z); d[3 * TSTR] = bf(fv[1].w);
      }
      f32x4 d0 = __builtin_amdgcn_mfma_f32_16x16x32_bf16(fa.v, fb0.v, zacc, 0, 0, 0);
      { uint2 w2; w2.x = pack_bf2(d0[0], d0[1]); w2.y = pack_bf2(d0[2], d0[3]);
        *reinterpret_cast<uint2*>(prow + (0 * 16 + l) * 16 + q * 4) = w2; }

      ABFrag fb1; fb1.u = make_uint4(0, 0, 0, 0);
      if (q < 2) fb1.v = *reinterpret_cast<const bf16x8*>(T0 + l * TSTR + q * 8);
      // f2 -> T1 (f0 consumed)
      {
        unsigned short* d = T1 + (sub * 4) * TSTR + kq;
        d[0 * TSTR] = bf(fv[2].x); d[1 * TSTR] = bf(fv[2].y);
        d[2 * TSTR] = bf(fv[2].z); d[3 * TSTR] = bf(fv[2].w);
      }
      f32x4 d1 = __builtin_amdgcn_mfma_f32_16x16x32_bf16(fa.v, fb1.v, zacc, 0, 0, 0);
      { uint2 w2; w2.x = pack_bf2(d1[0], d1[1]); w2.y = pack_bf2(d1[2], d1[3]);
        *reinterpret_cast<uint2*>(prow + (1 * 16 + l) * 16 + q * 4) = w2; }

      ABFrag fb2; fb2.u = make_uint4(0, 0, 0, 0);
      if (q < 2) fb2.v = *reinterpret_cast<const bf16x8*>(T1 + l * TSTR + q * 8);
      // f3 -> T0 (f1 consumed)
      {
        unsigned short* d = T0 + (sub * 4) * TSTR + kq;
        d[0 * TSTR] = bf(fv[3].x); d[1 * TSTR] = bf(fv[3].y);
        d[2 * TSTR] = bf(fv[3].z); d[3 * TSTR] = bf(fv[3].w);
      }
      f32x4 d2 = __builtin_amdgcn_mfma_f32_16x16x32_bf16(fa.v, fb2.v, zacc, 0, 0, 0);
      { uint2 w2; w2.x = pack_bf2(d2[0], d2[1]); w2.y = pack_bf2(d2[2], d2[3]);
        *reinterpret_cast<uint2*>(prow + (2 * 16 + l) * 16 + q * 4) = w2; }

      ABFrag fb3; fb3.u = make_uint4(0, 0, 0, 0);
      if (q < 2) fb3.v = *reinterpret_cast<const bf16x8*>(T0 + l * TSTR + q * 8);
      // addf tile -> T1 (f2 consumed): rows 0..2 = av, rows 3..15 = 0
      {
        if (lane < 52)
          *reinterpret_cast<uint2*>(T1 + (3 + (lane >> 2)) * TSTR + (lane & 3) * 4) =
              make_uint2(0u, 0u);
        if (sub < CADD)
          T1[sub * TSTR + kq] = bf(av[pl]);
      }
      f32x4 d3 = __builtin_amdgcn_mfma_f32_16x16x32_bf16(fa.v, fb3.v, zacc, 0, 0, 0);
      { uint2 w2; w2.x = pack_bf2(d3[0], d3[1]); w2.y = pack_bf2(d3[2], d3[3]);
        *reinterpret_cast<uint2*>(prow + (3 * 16 + l) * 16 + q * 4) = w2; }

      ABFrag fb4; fb4.u = make_uint4(0, 0, 0, 0);
      if (q < 2) fb4.v = *reinterpret_cast<const bf16x8*>(T1 + l * TSTR + q * 8);
      f32x4 d4 = __builtin_amdgcn_mfma_f32_16x16x32_bf16(fa.v, fb4.v, zacc, 0, 0, 0);
      if (l < 4) {  // c = 64..67 (67 is the K-pad row, genuinely zero)
        uint2 w2; w2.x = pack_bf2(d4[0], d4[1]); w2.y = pack_bf2(d4[2], d4[3]);
        *reinterpret_cast<uint2*>(prow + (4 * 16 + l) * 16 + q * 4) = w2;
      }
    }
  }

  __syncthreads();  // the ONLY barrier

  // ---------------- stage 2: out[32][128] = pconv[32][1088] @ Wb^T ----------------
  // each wave: 16 output channels x 32 points (two A tiles per Wb load -> 2-way
  // MFMA ILP); Wb streamed from L2 via a static 4-deep prefetch ring.
  const int ob = wid * 16;
  const float bv = bias[ob + l];

  f32x4 acc0 = {0.f, 0.f, 0.f, 0.f};
  f32x4 acc1 = {0.f, 0.f, 0.f, 0.f};

  const unsigned short* wp = Wb + (size_t)(ob + l) * KPAD + q * 8;
  const float* wf = W + (size_t)(ob + l) * KREAL + q * 8;

  if (useWb) {
    ABFrag wb[PF];
#pragma unroll
    for (int i = 0; i < PF; ++i)
      wb[i].u = *reinterpret_cast<const uint4*>(wp + i * 32);
#pragma unroll
    for (int kt = 0; kt < NKT; ++kt) {
      ABFrag cur = wb[kt & (PF - 1)];
      if (kt + PF < NKT)
        wb[kt & (PF - 1)].u = *reinterpret_cast<const uint4*>(wp + (kt + PF) * 32);
      const bf16x8 a0 = *reinterpret_cast<const bf16x8*>(
          s_p + l * PSTR + kt * 32 + q * 8);
      const bf16x8 a1 = *reinterpret_cast<const bf16x8*>(
          s_p + (16 + l) * PSTR + kt * 32 + q * 8);
      acc0 = __builtin_amdgcn_mfma_f32_16x16x32_bf16(a0, cur.v, acc0, 0, 0, 0);
      acc1 = __builtin_amdgcn_mfma_f32_16x16x32_bf16(a1, cur.v, acc1, 0, 0, 0);
    }
  } else {
#pragma unroll 2
    for (int kt = 0; kt < NKT; ++kt) {
      const bf16x8 a0 = *reinterpret_cast<const bf16x8*>(
          s_p + l * PSTR + kt * 32 + q * 8);
      const bf16x8 a1 = *reinterpret_cast<const bf16x8*>(
          s_p + (16 + l) * PSTR + kt * 32 + q * 8);
      const int kb = kt * 32 + q * 8;
      ABFrag bb;
      bb.u = make_uint4(0, 0, 0, 0);
      if (kb < KREAL) {
        const float4* s0 = reinterpret_cast<const float4*>(wf + kt * 32);
        const float4 x0 = s0[0], x1 = s0[1];
        bb.u = make_uint4(pack_bf2(x0.x, x0.y), pack_bf2(x0.z, x0.w),
                          pack_bf2(x1.x, x1.y), pack_bf2(x1.z, x1.w));
      }
      acc0 = __builtin_amdgcn_mfma_f32_16x16x32_bf16(a0, bb.v, acc0, 0, 0, 0);
      acc1 = __builtin_amdgcn_mfma_f32_16x16x32_bf16(a1, bb.v, acc1, 0, 0, 0);
    }
  }

  // epilogue: nt stores (out is never re-read)
  const int m0 = blockIdx.x * MT;
#pragma unroll
  for (int r = 0; r < 4; ++r) {
    __builtin_nontemporal_store(acc0[r] + bv,
        out + (size_t)(m0 + q * 4 + r) * COUT + ob + l);
    __builtin_nontemporal_store(acc1[r] + bv,
        out + (size_t)(m0 + 16 + q * 4 + r) * COUT + ob + l);
  }
}

extern "C" void kernel_launch(void* const* d_in, const int* in_sizes, int n_in,
                              void* d_out, int out_size, void* d_ws, size_t ws_size,
                              hipStream_t stream) {
  const float* feat = (const float*)d_in[0];
  const int*   nidx = (const int*)d_in[1];
  const float* wn   = (const float*)d_in[2];
  const float* addf = (const float*)d_in[3];
  const float* W    = (const float*)d_in[4];
  const float* bias = (const float*)d_in[5];
  float* out = (float*)d_out;

  unsigned short* Wb = (unsigned short*)d_ws;
  const int useWb = (ws_size >= (size_t)COUT * KPAD * 2) ? 1 : 0;
  if (useWb) {
    convert_w<<<COUT, 256, 0, stream>>>(W, Wb);
  }
  const int nblocks = (2 * NPTS) / MT;  // 4096
  pconv_fused<<<nblocks, 512, 0, stream>>>(feat, nidx, wn, addf, W, bias, Wb, useWb, out);
}